// Round 6
// baseline (108.724 us; speedup 1.0000x reference)
//
#include <hip/hip_runtime.h>
#include <hip/hip_bf16.h>

// Problem constants (from reference)
#define Bg 64       // graphs
#define Nn 256      // nodes per subgraph
#define Ee 2048     // edges per subgraph
#define Dd 128      // hidden dim
#define Hh 4        // heads
#define MAXJ 40     // cap on in-edges of node 0 (+self) per layer; Binom(2048,1/256): P(>38)~1e-17
#define RS 132      // LDS row stride (128 + 4 pad)
#define MAGIC 0x9E3779B1u   // flag value; workspace poison fill will never equal this

__device__ __forceinline__ float bf2f(unsigned short u) {
    return __uint_as_float(((unsigned)u) << 16);
}

// ---------------------------------------------------------------------------
// Fusion attempt #4: producer/consumer with LOAD-ONLY spin.
// History: two-kernel best = 103.4 us (r5). Fusions: r1 +6 (naive per-block
// fold), r4 +2.8 (cheap per-block fold), r3 +7 (flag sync, but spin was
// atomicAdd(fl,0) — a device-RMW; 512 lanes x 64 blocks RMW-convoy on one
// line serialized the producers' arming atomicExch behind it).
// This version: identical r5 consumer body; spin = relaxed agent-scope
// atomic LOAD (read-broadcast, no coherence-point serialization) + one
// acquire threadfence. Producers (blocks 0..7) = k1 at 512 threads.
// 72 blocks, 2/CU by LDS -> all co-resident on 256 CUs; no deadlock.
// Flags in poisoned workspace: reset each iteration, re-armed each launch.
// ---------------------------------------------------------------------------
__global__ __launch_bounds__(512) void gat_fused_kernel(
    const int* nn1, const int* nn2, const int* adj1, const int* adj2,
    const void* emb,
    const void* W1, const void* as1, const void* ad1, const void* b1,
    const void* W2, const void* as2, const void* ad2, const void* b2,
    const void* mlpw, const void* mlpb,
    float* wv, int f32arg, void* out)
{
    __shared__ float s_wv[24 * RS];            // 12.7 KB (producer: aliases s_av)
    __shared__ float s_rows[2 * MAXJ * RS];    // 42.2 KB (producer: aliases s_part)
    __shared__ int   s_nodes[2][Nn];           // 2 KB
    __shared__ int   s_srcj[2][MAXJ];
    __shared__ int   s_gid[2 * MAXJ];
    __shared__ int   s_cnt[2];
    __shared__ int   s_f32;
    __shared__ float s_ps[2 * MAXJ * Hh * 2], s_pm[2 * MAXJ * Hh * 2];
    __shared__ float s_pd[2 * Hh * 2], s_hval[2 * Hh], s_bdot[2];
    __shared__ float s_red[2];

    const int tid = threadIdx.x;
    const int x = blockIdx.x;

    if (x < 8) {
        // ================= PRODUCER (k1 at 512 threads) =================
        const int l = x >> 2, h = x & 3;
        float* s_av   = s_wv;     // 384 floats   [t][d]
        float* s_part = s_rows;   // 6144 floats  [dg][t][k]

        int f32 = f32arg;
        if (f32 < 0) {            // fallback dtype probe
            if (tid < 64) {
                float v = bf2f(((const unsigned short*)W1)[tid]);
                unsigned long long m = __ballot(!(v > -64.f && v < 64.f));
                if (tid == 0) s_f32 = (m != 0ull) ? 1 : 0;
            }
            __syncthreads();
            f32 = s_f32;
        }

        // stage the 3 fold vectors for this (l,h)
        if (tid < 384) {
            int t = tid >> 7, d = tid & 127;
            const void* p; long off;
            if (t == 0)      { p = l ? as2 : as1; off = (long)h * Dd + d; }
            else if (t == 1) { p = l ? ad2 : ad1; off = (long)h * Dd + d; }
            else             { p = mlpw;          off = (long)l * Dd + d; }
            s_av[tid] = f32 ? ((const float*)p)[off]
                            : bf2f(((const unsigned short*)p)[off]);
        }
        __syncthreads();

        // coalesced fold: 512 threads = 32 col-groups x 16 d-groups of 8
        {
            const int kc = (tid & 31) * 4;
            const int d0 = (tid >> 5) * 8;
            float acc[3][4] = {};
            if (f32) {
                const float* Wf = (const float*)(l ? W2 : W1) + (long)h * Dd * Dd;
                #pragma unroll
                for (int dd = 0; dd < 8; ++dd) {
                    int d = d0 + dd;
                    float4 w = *(const float4*)(Wf + (long)d * Dd + kc);
                    #pragma unroll
                    for (int t = 0; t < 3; ++t) {
                        float a = s_av[t * Dd + d];
                        acc[t][0] += a * w.x; acc[t][1] += a * w.y;
                        acc[t][2] += a * w.z; acc[t][3] += a * w.w;
                    }
                }
            } else {
                const unsigned short* Wb =
                    (const unsigned short*)(l ? W2 : W1) + (long)h * Dd * Dd;
                #pragma unroll
                for (int dd = 0; dd < 8; ++dd) {
                    int d = d0 + dd;
                    ushort4 u = *(const ushort4*)(Wb + (long)d * Dd + kc);
                    float wx = bf2f(u.x), wy = bf2f(u.y);
                    float wz = bf2f(u.z), ww = bf2f(u.w);
                    #pragma unroll
                    for (int t = 0; t < 3; ++t) {
                        float a = s_av[t * Dd + d];
                        acc[t][0] += a * wx; acc[t][1] += a * wy;
                        acc[t][2] += a * wz; acc[t][3] += a * ww;
                    }
                }
            }
            const int dg = tid >> 5;
            #pragma unroll
            for (int t = 0; t < 3; ++t)
                *(float4*)&s_part[(dg * 3 + t) * Dd + kc] =
                    make_float4(acc[t][0], acc[t][1], acc[t][2], acc[t][3]);
        }
        __syncthreads();

        // combine 16 d-groups -> 3 wv rows of this (l,h)
        if (tid < 384) {
            int t = tid >> 7, k = tid & 127;
            float s = 0.f;
            #pragma unroll
            for (int g = 0; g < 16; ++g) s += s_part[(g * 3 + t) * Dd + k];
            wv[((l * 3 + t) * 4 + h) * Dd + k] = s;
        }

        // bdot (blocks h==0): dot(bias_l, mlp_half_l) (+ mlp_b for l==0)
        if (h == 0) {            // block-uniform branch: barrier inside is safe
            float p = 0.f;
            if (tid < 128) {
                const void* bias = l ? b2 : b1;
                float bvv = f32 ? ((const float*)bias)[tid]
                                : bf2f(((const unsigned short*)bias)[tid]);
                p = bvv * s_av[2 * Dd + tid];
            }
            #pragma unroll
            for (int off = 32; off > 0; off >>= 1) p += __shfl_down(p, off);
            if (tid == 0 || tid == 64) s_red[tid >> 6] = p;
            __syncthreads();
            if (tid == 0) {
                float a = s_red[0] + s_red[1];
                if (l == 0) a += f32 ? ((const float*)mlpb)[0]
                                     : bf2f(((const unsigned short*)mlpb)[0]);
                wv[3072 + l] = a;
            }
        }

        // release: drain all waves' stores device-visible, then arm flag
        __threadfence();
        __syncthreads();
        if (tid == 0)
            atomicExch((unsigned*)wv + 3080 + x, MAGIC);
        return;
    }

    // ================= CONSUMER (r5 k2 body + load-spin) =================
    const int b = x - 8;

    // ---- pre-barrier phase: issue every independent load -----------------
    const int* adjp0 = adj1 + (long)b * 2 * Ee;
    const int* adjp1 = adj2 + (long)b * 2 * Ee;
    int4 d0 = ((const int4*)(adjp0 + Ee))[tid];   // dst halves (for ==0 test)
    int4 s0 = ((const int4*)adjp0)[tid];          // src halves (used on match)
    int4 d1 = ((const int4*)(adjp1 + Ee))[tid];
    int4 s1 = ((const int4*)adjp1)[tid];

    {   // node-id table: 512 threads == 2 layers x 256 nodes exactly
        int l = tid >> 8, n = tid & 255;
        s_nodes[l][n] = (l ? nn2 : nn1)[b * Nn + n];
    }
    if (tid < 2) s_cnt[tid] = 0;

    int f32 = f32arg;
    if (f32 < 0 && tid < 64) {    // fallback dtype probe
        float v = bf2f(((const unsigned short*)W1)[tid]);
        unsigned long long m = __ballot(!(v > -64.f && v < 64.f));
        if (tid == 0) s_f32 = (m != 0ull) ? 1 : 0;
    }
    __syncthreads();                                        // S1
    if (f32 < 0) f32 = s_f32;

    // ---- scan atomics (operands already in registers) --------------------
    {
        #define SCAN1(c, sv, l) \
            if ((c) == 0) { int p = atomicAdd(&s_cnt[l], 1); \
                            if (p < MAXJ - 1) s_srcj[l][p] = (sv); }
        SCAN1(d0.x, s0.x, 0) SCAN1(d0.y, s0.y, 0)
        SCAN1(d0.z, s0.z, 0) SCAN1(d0.w, s0.w, 0)
        SCAN1(d1.x, s1.x, 1) SCAN1(d1.y, s1.y, 1)
        SCAN1(d1.z, s1.z, 1) SCAN1(d1.w, s1.w, 1)
        #undef SCAN1
    }
    __syncthreads();                                        // S2

    // ---- counts + gid (self-loop fused in, row LAST within each layer) ---
    int c0 = s_cnt[0]; if (c0 > MAXJ - 1) c0 = MAXJ - 1; c0 += 1;
    int c1 = s_cnt[1]; if (c1 > MAXJ - 1) c1 = MAXJ - 1; c1 += 1;
    const int tot = c0 + c1;

    if (tid < 2 * MAXJ) {
        int l = tid >= MAXJ;
        int j = l ? tid - MAXJ : tid;
        int cl = l ? c1 : c0;
        int base = l ? c0 : 0;
        if (j < cl) {
            int src = (j == cl - 1) ? 0 : s_srcj[l][j];   // self-loop last
            s_gid[base + j] = s_nodes[l][src];
        }
    }
    __syncthreads();                                        // S3

    // ---- gather embedding rows (overlaps producers' fold) ----------------
    if (f32) {
        for (int idx = tid; idx < tot * 32; idx += 512) {
            int j = idx >> 5, k4 = (idx & 31) << 2;
            long gid = s_gid[j];
            float4 f = ((const float4*)emb)[gid * 32 + (k4 >> 2)];
            *(float4*)&s_rows[j * RS + k4] = f;
        }
    } else {
        for (int idx = tid; idx < tot * 16; idx += 512) {
            int j = idx >> 4, k8 = (idx & 15) << 3;
            long gid = s_gid[j];
            uint4 u = *(const uint4*)((const unsigned short*)emb + gid * Dd + k8);
            float4 f0 = make_float4(bf2f(u.x & 0xffff), bf2f(u.x >> 16),
                                    bf2f(u.y & 0xffff), bf2f(u.y >> 16));
            float4 f1 = make_float4(bf2f(u.z & 0xffff), bf2f(u.z >> 16),
                                    bf2f(u.w & 0xffff), bf2f(u.w >> 16));
            *(float4*)&s_rows[j * RS + k8] = f0;
            *(float4*)&s_rows[j * RS + k8 + 4] = f1;
        }
    }

    // ---- spin on producer flags: LOAD-only (no RMW convoy) ---------------
    if (tid < 8) {
        const unsigned* fl = (const unsigned*)wv + 3080 + tid;
        while (__hip_atomic_load(fl, __ATOMIC_RELAXED,
                                 __HIP_MEMORY_SCOPE_AGENT) != MAGIC)
            __builtin_amdgcn_s_sleep(2);
    }
    __syncthreads();                                        // S4
    __threadfence();   // acquire: no stale wv lines past this point

    // ---- stage wv + bdot --------------------------------------------------
    for (int i = tid; i < 768; i += 512) {
        float4 f = ((const float4*)wv)[i];
        int el = i * 4, row = el >> 7, k = el & 127;
        *(float4*)&s_wv[row * RS + k] = f;
    }
    if (tid < 2) s_bdot[tid] = wv[3072 + tid];
    __syncthreads();                                        // S5

    // ---- dots (half-split): task = (old_task, kk half) -------------------
    const int ntask = (tot * 8 + 8) * 2;
    for (int task = tid; task < ntask; task += 512) {
        const int kk = task & 1;          // which 64-element half of the dot
        const int t0 = task >> 1;
        int j, h, t, l;
        if (t0 < tot * 8) {
            j = t0 >> 3; h = (t0 >> 1) & 3; t = (t0 & 1) ? 2 : 0;
            l = (j < c0) ? 0 : 1;
        } else {
            int z = t0 - tot * 8;         // 0..7
            l = z >> 2; h = z & 3; t = 1;
            j = l ? (tot - 1) : (c0 - 1); // self-loop row = center node
        }
        const float4* r4 = (const float4*)(s_rows + j * RS) + kk * 16;
        const float4* w4 = (const float4*)(s_wv + ((l * 3 + t) * Hh + h) * RS) + kk * 16;
        float acc = 0.f;
        #pragma unroll
        for (int k = 0; k < 16; ++k) {
            float4 a = r4[k], w = w4[k];
            acc += a.x * w.x + a.y * w.y + a.z * w.z + a.w * w.w;
        }
        if (t0 < tot * 8) {
            if (t0 & 1) s_pm[(j * Hh + h) * 2 + kk] = acc;
            else        s_ps[(j * Hh + h) * 2 + kk] = acc;
        } else {
            s_pd[((l << 2) | h) * 2 + kk] = acc;
        }
    }
    __syncthreads();                                        // S6

    // ---- wave-parallel softmax: wave w=(l,h), lanes parallel over j ------
    {
        const int w = tid >> 6, lane = tid & 63;
        const int l = w >> 2, h = w & 3;
        const int j0 = l ? c0 : 0;
        const int cntl = (l ? tot : c0) - j0;     // <= MAXJ <= 64 lanes
        const float pd = s_pd[w * 2] + s_pd[w * 2 + 1];
        const bool valid = lane < cntl;
        const int j = j0 + (valid ? lane : 0);
        float e = valid ? (s_ps[(j * Hh + h) * 2] + s_ps[(j * Hh + h) * 2 + 1] + pd)
                        : -1e30f;
        e = (e >= 0.f) ? e : 0.2f * e;            // leaky relu, slope 0.2
        float m = e;
        #pragma unroll
        for (int off = 32; off > 0; off >>= 1)
            m = fmaxf(m, __shfl_xor(m, off));
        float ex = valid ? expf(e - m) : 0.f;
        float pm = valid ? (s_pm[(j * Hh + h) * 2] + s_pm[(j * Hh + h) * 2 + 1]) : 0.f;
        float den = ex, num = ex * pm;
        #pragma unroll
        for (int off = 32; off > 0; off >>= 1) {
            den += __shfl_xor(den, off);
            num += __shfl_xor(num, off);
        }
        if (lane == 0) s_hval[w] = num / den;
    }
    __syncthreads();                                        // S7

    if (tid == 0) {
        float r = 0.25f * (s_hval[0] + s_hval[1] + s_hval[2] + s_hval[3]) + s_bdot[0]
                + 0.25f * (s_hval[4] + s_hval[5] + s_hval[6] + s_hval[7]) + s_bdot[1];
        if (f32) ((float*)out)[b] = r;
        else     ((__hip_bfloat16*)out)[b] = __float2bfloat16(r);
    }
}

extern "C" void kernel_launch(void* const* d_in, const int* in_sizes, int n_in,
                              void* d_out, int out_size, void* d_ws, size_t ws_size,
                              hipStream_t stream) {
    float* wv = (float*)d_ws;   // floats 0..3073 = wv+bdot; words 3080..3087 = flags

    // dtype from host-side byte sizes (W1 = 512x128 elems); -1 -> device probe
    int sz5 = (in_sizes && n_in > 5) ? in_sizes[5] : 0;
    int f32arg = (sz5 == 512 * 128 * 4) ? 1 : ((sz5 == 512 * 128 * 2) ? 0 : -1);

    gat_fused_kernel<<<8 + Bg, 512, 0, stream>>>(
        (const int*)d_in[0],  /* nn1 */
        (const int*)d_in[1],  /* nn2 */
        (const int*)d_in[2],  /* adj1 */
        (const int*)d_in[3],  /* adj2 */
        d_in[4],  /* emb */
        d_in[5],  /* W1  */ d_in[6],  /* as1 */ d_in[7],  /* ad1 */
        d_in[8],  /* b1  */
        d_in[9],  /* W2  */ d_in[10], /* as2 */ d_in[11], /* ad2 */
        d_in[12], /* b2  */
        d_in[13], /* mlpw */ d_in[14], /* mlpb */
        wv, f32arg, d_out);
}

// Round 7
// 104.890 us; speedup vs baseline: 1.0366x; 1.0366x over previous
//
#include <hip/hip_runtime.h>
#include <hip/hip_bf16.h>

// Problem constants (from reference)
#define Bg 64       // graphs
#define Nn 256      // nodes per subgraph
#define Ee 2048     // edges per subgraph
#define Dd 128      // hidden dim
#define Hh 4        // heads
#define MAXJ 40     // cap on in-edges of node 0 (+self) per layer; Binom(2048,1/256): P(>38)~1e-17
#define RS 132      // LDS row stride (128 + 4 pad)

__device__ __forceinline__ float bf2f(unsigned short u) {
    return __uint_as_float(((unsigned)u) << 16);
}

// ---------------------------------------------------------------------------
// Two-kernel structure: measured best (103.4 us r5). FOUR single-dispatch
// fusion strategies all regressed vs this:
//  - per-block wv recompute, naive (r1):           +6.2 us
//  - producer/consumer, RMW spin (r3):             +7.1 us
//  - per-block recompute, 16B fold + T14 (r4):     +2.8 us
//  - producer/consumer, load-only spin (r6):       +5.3 us
// Mechanism: any in-kernel wv dependency puts either a cold-W read or a
// chip-global sync point (spin + acquire fence + cold-L1 reload) on all 64
// consumer blocks' critical paths; the two-launch pipeline handles the
// dependency in the command processor, off every wave's critical path.
// Kernel 1 reads W once chip-wide (8 blocks); kernel 2 reads only the 12 KB
// folded table. Remaining time = 2 x 43.5 us harness poison fills (HBM
// roofline, not ours) + ~16 us kernels/launch overhead.
// ---------------------------------------------------------------------------

// Kernel 1: wv fold + bdot, fully COALESCED W reads.
// Grid: 8 blocks = (l = x>>2, h = x&3), 256 threads.
//   wv[((l*3+t)*4+h)*128 + k] = sum_d av_t[d] * W_l[h*128+d, k]
//     t: 0=att_src, 1=att_dst, 2=mlp half.  wv[3072+l] = bdot_l.
__global__ __launch_bounds__(256) void precompute_kernel(
    const void* W1, const void* as1, const void* ad1, const void* b1,
    const void* W2, const void* as2, const void* ad2, const void* b2,
    const void* mlpw, const void* mlpb, float* wv)
{
    __shared__ float s_av[3 * Dd];         // [t][d]
    __shared__ float s_part[8 * 3 * Dd];   // [dg][t][k]  12 KB
    __shared__ float s_red[2];
    __shared__ int   s_f32;

    const int tid = threadIdx.x;
    const int x = blockIdx.x;
    const int l = x >> 2, h = x & 3;

    // dtype probe (W1 is read by this kernel anyway; zero marginal cost)
    if (tid < 64) {
        float v = bf2f(((const unsigned short*)W1)[tid]);
        bool bad = !(v > -64.f && v < 64.f);
        unsigned long long m = __ballot(bad);
        if (tid == 0) s_f32 = (m != 0ull) ? 1 : 0;
    }
    __syncthreads();
    const int f32 = s_f32;

    // stage the 3 attention vectors for this (l,h)
    for (int i = tid; i < 3 * Dd; i += 256) {
        int t = i >> 7, d = i & 127;
        const void* p; long off;
        if (t == 0)      { p = l ? as2 : as1; off = (long)h * Dd + d; }
        else if (t == 1) { p = l ? ad2 : ad1; off = (long)h * Dd + d; }
        else             { p = mlpw;          off = (long)l * Dd + d; }
        s_av[i] = f32 ? ((const float*)p)[off]
                      : bf2f(((const unsigned short*)p)[off]);
    }
    __syncthreads();

    // coalesced fold
    {
        const int kc = (tid & 31) * 4;
        const int d0 = (tid >> 5) * 16;
        float acc[3][4] = {};
        if (f32) {
            const float* Wf = (const float*)(l ? W2 : W1) + (long)h * Dd * Dd;
            #pragma unroll
            for (int dd = 0; dd < 16; ++dd) {
                int d = d0 + dd;
                float4 w = *(const float4*)(Wf + (long)d * Dd + kc);
                #pragma unroll
                for (int t = 0; t < 3; ++t) {
                    float a = s_av[t * Dd + d];
                    acc[t][0] += a * w.x; acc[t][1] += a * w.y;
                    acc[t][2] += a * w.z; acc[t][3] += a * w.w;
                }
            }
        } else {
            const unsigned short* Wb =
                (const unsigned short*)(l ? W2 : W1) + (long)h * Dd * Dd;
            #pragma unroll
            for (int dd = 0; dd < 16; ++dd) {
                int d = d0 + dd;
                ushort4 u = *(const ushort4*)(Wb + (long)d * Dd + kc);
                float wx = bf2f(u.x), wy = bf2f(u.y);
                float wz = bf2f(u.z), ww = bf2f(u.w);
                #pragma unroll
                for (int t = 0; t < 3; ++t) {
                    float a = s_av[t * Dd + d];
                    acc[t][0] += a * wx; acc[t][1] += a * wy;
                    acc[t][2] += a * wz; acc[t][3] += a * ww;
                }
            }
        }
        const int dg = tid >> 5;
        #pragma unroll
        for (int t = 0; t < 3; ++t)
            *(float4*)&s_part[(dg * 3 + t) * Dd + kc] =
                make_float4(acc[t][0], acc[t][1], acc[t][2], acc[t][3]);
    }
    __syncthreads();

    // combine 8 d-groups -> 3 wv rows of this (l,h)
    for (int i = tid; i < 3 * Dd; i += 256) {
        int t = i >> 7, k = i & 127;
        float s = 0.f;
        #pragma unroll
        for (int g = 0; g < 8; ++g) s += s_part[(g * 3 + t) * Dd + k];
        wv[((l * 3 + t) * 4 + h) * Dd + k] = s;
    }

    // bdot (blocks h==0): dot(bias_l, mlp_half_l) (+ mlp_b for l==0)
    if (h == 0) {
        float p = 0.f;
        if (tid < 128) {
            const void* bias = l ? b2 : b1;
            float bv = f32 ? ((const float*)bias)[tid]
                           : bf2f(((const unsigned short*)bias)[tid]);
            p = bv * s_av[2 * Dd + tid];
        }
        #pragma unroll
        for (int off = 32; off > 0; off >>= 1) p += __shfl_down(p, off);
        if (tid == 0 || tid == 64) s_red[tid >> 6] = p;
        __syncthreads();
        if (tid == 0) {
            float a = s_red[0] + s_red[1];
            if (l == 0) a += f32 ? ((const float*)mlpb)[0]
                                 : bf2f(((const unsigned short*)mlpb)[0]);
            wv[3072 + l] = a;
        }
    }
}

// ---------------------------------------------------------------------------
// Kernel 2: one block per graph, both layers, 512 threads (8 waves).
//  - ALL independent HBM loads (adj dst AND src int4s, node table) issued
//    before the first barrier; dtype comes from the HOST (no cold W1 probe).
//  - Self-loop append fused into the gid phase.
//  - Dots are HALF-SPLIT: each 128-FMA dot = two 64-FMA tasks (partials
//    summed at softmax read) -> 2x task parallelism, half the dep chain.
//  - Softmax is wave-parallel: wave w=(l,h), lanes over in-edges, __shfl_xor.
// ---------------------------------------------------------------------------
__global__ __launch_bounds__(512) void gat_main_kernel(
    const int* nn1, const int* nn2, const int* adj1, const int* adj2,
    const void* emb, const void* W1, const float* wv, int f32arg, void* out)
{
    __shared__ float s_wv[24 * RS];            // 12.7 KB
    __shared__ float s_rows[2 * MAXJ * RS];    // 42.2 KB
    __shared__ int   s_nodes[2][Nn];           // 2 KB
    __shared__ int   s_srcj[2][MAXJ];
    __shared__ int   s_gid[2 * MAXJ];
    __shared__ int   s_cnt[2];
    __shared__ int   s_f32;
    __shared__ float s_ps[2 * MAXJ * Hh * 2], s_pm[2 * MAXJ * Hh * 2];
    __shared__ float s_pd[2 * Hh * 2], s_hval[2 * Hh], s_bdot[2];

    const int tid = threadIdx.x;
    const int b = blockIdx.x;

    // ---- pre-barrier phase: issue every independent load -----------------
    const int* adjp0 = adj1 + (long)b * 2 * Ee;
    const int* adjp1 = adj2 + (long)b * 2 * Ee;
    int4 d0 = ((const int4*)(adjp0 + Ee))[tid];   // dst halves (for ==0 test)
    int4 s0 = ((const int4*)adjp0)[tid];          // src halves (used on match)
    int4 d1 = ((const int4*)(adjp1 + Ee))[tid];
    int4 s1 = ((const int4*)adjp1)[tid];

    {   // node-id table: 512 threads == 2 layers x 256 nodes exactly
        int l = tid >> 8, n = tid & 255;
        s_nodes[l][n] = (l ? nn2 : nn1)[b * Nn + n];
    }
    if (tid < 2) s_cnt[tid] = 0;

    int f32 = f32arg;
    if (f32 < 0 && tid < 64) {    // fallback dtype probe (host sizes odd)
        float v = bf2f(((const unsigned short*)W1)[tid]);
        unsigned long long m = __ballot(!(v > -64.f && v < 64.f));
        if (tid == 0) s_f32 = (m != 0ull) ? 1 : 0;
    }
    __syncthreads();                                        // S1
    if (f32 < 0) f32 = s_f32;

    // ---- scan atomics (operands already in registers) --------------------
    {
        #define SCAN1(c, sv, l) \
            if ((c) == 0) { int p = atomicAdd(&s_cnt[l], 1); \
                            if (p < MAXJ - 1) s_srcj[l][p] = (sv); }
        SCAN1(d0.x, s0.x, 0) SCAN1(d0.y, s0.y, 0)
        SCAN1(d0.z, s0.z, 0) SCAN1(d0.w, s0.w, 0)
        SCAN1(d1.x, s1.x, 1) SCAN1(d1.y, s1.y, 1)
        SCAN1(d1.z, s1.z, 1) SCAN1(d1.w, s1.w, 1)
        #undef SCAN1
    }

    // wv stage (768 float4 / 512 threads = 2 iters) + bdot
    for (int i = tid; i < 768; i += 512) {
        float4 f = ((const float4*)wv)[i];
        int el = i * 4, row = el >> 7, k = el & 127;
        *(float4*)&s_wv[row * RS + k] = f;
    }
    if (tid < 2) s_bdot[tid] = wv[3072 + tid];
    __syncthreads();                                        // S2

    // ---- counts + gid (self-loop fused in, row LAST within each layer) ---
    int c0 = s_cnt[0]; if (c0 > MAXJ - 1) c0 = MAXJ - 1; c0 += 1;
    int c1 = s_cnt[1]; if (c1 > MAXJ - 1) c1 = MAXJ - 1; c1 += 1;
    const int tot = c0 + c1;

    if (tid < 2 * MAXJ) {
        int l = tid >= MAXJ;
        int j = l ? tid - MAXJ : tid;
        int cl = l ? c1 : c0;
        int base = l ? c0 : 0;
        if (j < cl) {
            int src = (j == cl - 1) ? 0 : s_srcj[l][j];   // self-loop last
            s_gid[base + j] = s_nodes[l][src];
        }
    }
    __syncthreads();                                        // S3

    // ---- gather embedding rows ------------------------------------------
    if (f32) {
        for (int idx = tid; idx < tot * 32; idx += 512) {
            int j = idx >> 5, k4 = (idx & 31) << 2;
            long gid = s_gid[j];
            float4 f = ((const float4*)emb)[gid * 32 + (k4 >> 2)];
            *(float4*)&s_rows[j * RS + k4] = f;
        }
    } else {
        for (int idx = tid; idx < tot * 16; idx += 512) {
            int j = idx >> 4, k8 = (idx & 15) << 3;
            long gid = s_gid[j];
            uint4 u = *(const uint4*)((const unsigned short*)emb + gid * Dd + k8);
            float4 f0 = make_float4(bf2f(u.x & 0xffff), bf2f(u.x >> 16),
                                    bf2f(u.y & 0xffff), bf2f(u.y >> 16));
            float4 f1 = make_float4(bf2f(u.z & 0xffff), bf2f(u.z >> 16),
                                    bf2f(u.w & 0xffff), bf2f(u.w >> 16));
            *(float4*)&s_rows[j * RS + k8] = f0;
            *(float4*)&s_rows[j * RS + k8 + 4] = f1;
        }
    }
    __syncthreads();                                        // S4

    // ---- dots (half-split): task = (old_task, kk half) -------------------
    // old_task < tot*8: row j, head h, t in {asrc, pm}; else adst(center).
    const int ntask = (tot * 8 + 8) * 2;
    for (int task = tid; task < ntask; task += 512) {
        const int kk = task & 1;          // which 64-element half of the dot
        const int t0 = task >> 1;
        int j, h, t, l;
        if (t0 < tot * 8) {
            j = t0 >> 3; h = (t0 >> 1) & 3; t = (t0 & 1) ? 2 : 0;
            l = (j < c0) ? 0 : 1;
        } else {
            int z = t0 - tot * 8;         // 0..7
            l = z >> 2; h = z & 3; t = 1;
            j = l ? (tot - 1) : (c0 - 1); // self-loop row = center node
        }
        const float4* r4 = (const float4*)(s_rows + j * RS) + kk * 16;
        const float4* w4 = (const float4*)(s_wv + ((l * 3 + t) * Hh + h) * RS) + kk * 16;
        float acc = 0.f;
        #pragma unroll
        for (int k = 0; k < 16; ++k) {
            float4 a = r4[k], w = w4[k];
            acc += a.x * w.x + a.y * w.y + a.z * w.z + a.w * w.w;
        }
        if (t0 < tot * 8) {
            if (t0 & 1) s_pm[(j * Hh + h) * 2 + kk] = acc;
            else        s_ps[(j * Hh + h) * 2 + kk] = acc;
        } else {
            s_pd[((l << 2) | h) * 2 + kk] = acc;
        }
    }
    __syncthreads();                                        // S5

    // ---- wave-parallel softmax: wave w=(l,h), lanes parallel over j ------
    {
        const int w = tid >> 6, lane = tid & 63;
        const int l = w >> 2, h = w & 3;
        const int j0 = l ? c0 : 0;
        const int cntl = (l ? tot : c0) - j0;     // <= MAXJ <= 64 lanes
        const float pd = s_pd[w * 2] + s_pd[w * 2 + 1];
        const bool valid = lane < cntl;
        const int j = j0 + (valid ? lane : 0);
        float e = valid ? (s_ps[(j * Hh + h) * 2] + s_ps[(j * Hh + h) * 2 + 1] + pd)
                        : -1e30f;
        e = (e >= 0.f) ? e : 0.2f * e;            // leaky relu, slope 0.2
        float m = e;
        #pragma unroll
        for (int off = 32; off > 0; off >>= 1)
            m = fmaxf(m, __shfl_xor(m, off));
        float ex = valid ? expf(e - m) : 0.f;
        float pm = valid ? (s_pm[(j * Hh + h) * 2] + s_pm[(j * Hh + h) * 2 + 1]) : 0.f;
        float den = ex, num = ex * pm;
        #pragma unroll
        for (int off = 32; off > 0; off >>= 1) {
            den += __shfl_xor(den, off);
            num += __shfl_xor(num, off);
        }
        if (lane == 0) s_hval[w] = num / den;
    }
    __syncthreads();                                        // S6

    if (tid == 0) {
        float r = 0.25f * (s_hval[0] + s_hval[1] + s_hval[2] + s_hval[3]) + s_bdot[0]
                + 0.25f * (s_hval[4] + s_hval[5] + s_hval[6] + s_hval[7]) + s_bdot[1];
        if (f32) ((float*)out)[b] = r;
        else     ((__hip_bfloat16*)out)[b] = __float2bfloat16(r);
    }
}

extern "C" void kernel_launch(void* const* d_in, const int* in_sizes, int n_in,
                              void* d_out, int out_size, void* d_ws, size_t ws_size,
                              hipStream_t stream) {
    const int* nn1  = (const int*)d_in[0];
    const int* nn2  = (const int*)d_in[1];
    const int* adj1 = (const int*)d_in[2];
    const int* adj2 = (const int*)d_in[3];
    float* wv = (float*)d_ws;     // 3074 fp32, fully rewritten every launch

    // dtype from host-side byte sizes (W1 = 512x128 elems); -1 -> device probe
    int sz5 = (in_sizes && n_in > 5) ? in_sizes[5] : 0;
    int f32arg = (sz5 == 512 * 128 * 4) ? 1 : ((sz5 == 512 * 128 * 2) ? 0 : -1);

    precompute_kernel<<<8, 256, 0, stream>>>(
        d_in[5],  /* W1  */ d_in[6],  /* as1 */ d_in[7],  /* ad1 */
        d_in[8],  /* b1  */
        d_in[9],  /* W2  */ d_in[10], /* as2 */ d_in[11], /* ad2 */
        d_in[12], /* b2  */
        d_in[13], /* mlpw */ d_in[14], /* mlpb */ wv);

    gat_main_kernel<<<Bg, 512, 0, stream>>>(
        nn1, nn2, adj1, adj2, d_in[4] /* emb */, d_in[5] /* W1 */, wv,
        f32arg, d_out);
}